// Round 1
// baseline (315.298 us; speedup 1.0000x reference)
//
#include <hip/hip_runtime.h>
#include <math.h>

#define BB 8
#define NN 8192
#define DD 128
#define MM 256
#define DVV 128
#define PP 32        // split-N partial blocks per batch
#define CHUNK 32     // tokens per chunk

#define XSCALE 0.29730177875068026f
#define INV_SQRT_M 0.0625f

typedef _Float16 f16x8 __attribute__((ext_vector_type(8)));
typedef float f32x16 __attribute__((ext_vector_type(16)));

// LDS fragment slab: 64 lanes x 8 halves, stride 520 (16B-aligned, bank-spread)
#define FR(s, l) ((s) * 520 + (l) * 8)

__device__ __forceinline__ unsigned f2ord(float f) {
    unsigned u = __float_as_uint(f);
    return (u & 0x80000000u) ? ~u : (u | 0x80000000u);
}
__device__ __forceinline__ float ord2f(unsigned u) {
    return (u & 0x80000000u) ? __uint_as_float(u & 0x7fffffffu) : __uint_as_float(~u);
}
__device__ __forceinline__ f32x16 mfma16(f16x8 a, f16x8 b, f32x16 c) {
    return __builtin_amdgcn_mfma_f32_32x32x16_f16(a, b, c, 0, 0, 0);
}
__device__ __forceinline__ int rowf(int r, int q) { return (r & 3) + 8 * (r >> 2) + 4 * q; }

// Stage X (A-operand): src row-major [32][128] fp32 -> scaled hi/lo f16 frags in R1.
// Slabs: comp*8 + ks (ks = k/16). Also h (=0.5*sum xs^2) and mask.
__device__ __forceinline__ void stage_A(const float* __restrict__ src,
                                        _Float16* R1, float* hs, float* msk,
                                        const float* __restrict__ mrow, bool do_h) {
    const int tid = threadIdx.x;
    const int t = tid >> 3, ks = tid & 7;
    const float4* s4 = (const float4*)(src + t * DD + ks * 16);
    float x[16];
    #pragma unroll
    for (int u = 0; u < 4; ++u) {
        float4 v = s4[u];
        x[u*4+0] = v.x * XSCALE; x[u*4+1] = v.y * XSCALE;
        x[u*4+2] = v.z * XSCALE; x[u*4+3] = v.w * XSCALE;
    }
    if (do_h) {
        float p = 0.f;
        #pragma unroll
        for (int u = 0; u < 16; ++u) p += x[u] * x[u];
        p += __shfl_xor(p, 1, 64); p += __shfl_xor(p, 2, 64); p += __shfl_xor(p, 4, 64);
        if (ks == 0) { hs[t] = 0.5f * p; msk[t] = mrow[t]; }
    }
    #pragma unroll
    for (int q = 0; q < 2; ++q) {
        f16x8 h8, l8;
        #pragma unroll
        for (int j = 0; j < 8; ++j) {
            float xv = x[q*8 + j];
            _Float16 h = (_Float16)xv;
            h8[j] = h; l8[j] = (_Float16)(xv - (float)h);
        }
        *(f16x8*)&R1[FR(0*8 + ks, q*32 + t)] = h8;
        *(f16x8*)&R1[FR(1*8 + ks, q*32 + t)] = l8;
    }
}

// Stage V (B-operand): src [32 rows=k][128 cols=n] fp32 -> hi/lo frags in R1.
// Slabs: (comp*4 + vt)*2 + tstep.
__device__ __forceinline__ void stage_BV(const float* __restrict__ src, _Float16* R1) {
    const int tid = threadIdx.x;
    const int t = tid >> 3, c0 = (tid & 7) * 16;
    const int ts = t >> 4, qq = (t >> 3) & 1, j = t & 7;
    const float4* s4 = (const float4*)(src + t * DVV + c0);
    #pragma unroll
    for (int u = 0; u < 4; ++u) {
        float4 v = s4[u];
        float vv[4] = {v.x, v.y, v.z, v.w};
        #pragma unroll
        for (int e = 0; e < 4; ++e) {
            int c = c0 + u*4 + e;
            int vt = c >> 5, iv = c & 31;
            _Float16 h = (_Float16)vv[e];
            R1[FR((0*4 + vt)*2 + ts, qq*32 + iv) + j] = h;
            R1[FR((1*4 + vt)*2 + ts, qq*32 + iv) + j] = (_Float16)(vv[e] - (float)h);
        }
    }
}

// ---------------------------------------------------------------------------
// pack: omega -> B-frag layout hi/lo f16 in ws; init kmaxord
// ---------------------------------------------------------------------------
__global__ __launch_bounds__(256) void pack_kernel(const float* __restrict__ omega,
                                                   _Float16* __restrict__ omh,
                                                   _Float16* __restrict__ oml,
                                                   unsigned* __restrict__ kmaxord) {
    int g = blockIdx.x * 256 + threadIdx.x;    // 0..4095
    if (g < BB) kmaxord[g] = f2ord(-INFINITY);
    int lane = g & 63, ks = (g >> 6) & 7, nt = g >> 9;
    int q = lane >> 5, i = lane & 31;
    f16x8 h8, l8;
    #pragma unroll
    for (int j = 0; j < 8; ++j) {
        float w = omega[(size_t)(ks*16 + q*8 + j) * MM + nt*32 + i];
        _Float16 h = (_Float16)w;
        h8[j] = h; l8[j] = (_Float16)(w - (float)h);
    }
    ((f16x8*)omh)[g] = h8;
    ((f16x8*)oml)[g] = l8;
}

// ---------------------------------------------------------------------------
// kmax: per-batch max of U_K (hi*hi only -- mx error cancels in the ratio)
// grid.x = 64 (4 chunks/block) -> 2 blocks/CU for latency overlap
// ---------------------------------------------------------------------------
__global__ __launch_bounds__(256, 2) void kmax_kernel(const float* __restrict__ K,
                                                      const _Float16* __restrict__ omh,
                                                      unsigned* __restrict__ kmaxord) {
    __shared__ __align__(16) _Float16 R1[16 * 520];
    __shared__ float wred[4];
    const int b = blockIdx.y;
    const int tid = threadIdx.x, w = tid >> 6, lane = tid & 63;

    f16x8 om[2][8];
    #pragma unroll
    for (int n = 0; n < 2; ++n)
        #pragma unroll
        for (int k = 0; k < 8; ++k)
            om[n][k] = ((const f16x8*)omh)[((2*w + n)*8 + k)*64 + lane];

    float mx = -INFINITY;
    for (int c = 0; c < 4; ++c) {
        int t0 = (blockIdx.x * 4 + c) * CHUNK;
        __syncthreads();
        stage_A(K + ((size_t)b*NN + t0) * DD, R1, nullptr, nullptr, nullptr, false);
        __syncthreads();
        f32x16 a0, a1;
        #pragma unroll
        for (int r = 0; r < 16; ++r) { a0[r] = 0.f; a1[r] = 0.f; }
        #pragma unroll
        for (int ks = 0; ks < 8; ++ks) {
            f16x8 ah = *(const f16x8*)&R1[FR(ks, lane)];
            a0 = mfma16(ah, om[0][ks], a0);
            a1 = mfma16(ah, om[1][ks], a1);
        }
        #pragma unroll
        for (int r = 0; r < 16; ++r) mx = fmaxf(mx, fmaxf(a0[r], a1[r]));
    }
    #pragma unroll
    for (int off = 1; off < 64; off <<= 1) mx = fmaxf(mx, __shfl_xor(mx, off, 64));
    if (lane == 0) wred[w] = mx;
    __syncthreads();
    if (tid == 0)
        atomicMax(kmaxord + b,
                  f2ord(fmaxf(fmaxf(wred[0], wred[1]), fmaxf(wred[2], wred[3]))));
}

// ---------------------------------------------------------------------------
// kv: U_K (3-mfma split) -> Kp -> LDS transpose -> KV = Kp^T V (3-mfma split)
// Feature-split: 2 blocks per p-slot, each owns 128 of 256 features.
//  -> 512 blocks (2/CU), omf/kvacc halved (~200 VGPR), R2 halved (16 slabs).
//  (p,h) pairs share bx%8 so the duplicate K/V chunk read hits the same XCD L2.
// ---------------------------------------------------------------------------
__global__ __launch_bounds__(256, 2) void kv_kernel(const float* __restrict__ K,
                                                    const float* __restrict__ V,
                                                    const float* __restrict__ mask,
                                                    const _Float16* __restrict__ omh,
                                                    const _Float16* __restrict__ oml,
                                                    const unsigned* __restrict__ kmaxord,
                                                    float* __restrict__ pkv,
                                                    float* __restrict__ pks) {
    __shared__ __align__(16) _Float16 R1[16 * 520];
    __shared__ __align__(16) _Float16 R2[16 * 520];
    __shared__ float hs[32], msk[32];
    const int b = blockIdx.y, bx = blockIdx.x;
    const int rest = bx >> 3;
    const int h = rest & 1;                      // feature half 0/1
    const int p = (rest >> 1) * 8 + (bx & 7);    // N-split slot 0..31
    const int tid = threadIdx.x, w = tid >> 6, lane = tid & 63;
    const int i = tid & 31, q = (tid >> 5) & 1;
    const int nt = h * 4 + w;                    // this wave's 32-feature block (0..7)
    const float kmaxv = ord2f(kmaxord[b]);

    f16x8 omf[2][8];   // [comp][ks]
    #pragma unroll
    for (int k = 0; k < 8; ++k) {
        omf[0][k] = ((const f16x8*)omh)[(nt*8 + k)*64 + lane];
        omf[1][k] = ((const f16x8*)oml)[(nt*8 + k)*64 + lane];
    }

    f32x16 kvacc[4];
    #pragma unroll
    for (int vt = 0; vt < 4; ++vt)
        #pragma unroll
        for (int r = 0; r < 16; ++r) kvacc[vt][r] = 0.f;
    float ksa = 0.f;

    for (int c = 0; c < 8; ++c) {
        int t0 = (p * 8 + c) * CHUNK;
        __syncthreads();
        stage_A(K + ((size_t)b*NN + t0) * DD, R1, hs, msk,
                mask + (size_t)b*NN + t0, true);
        __syncthreads();

        f32x16 a0;
        #pragma unroll
        for (int r = 0; r < 16; ++r) a0[r] = 0.f;
        #pragma unroll
        for (int ks = 0; ks < 8; ++ks) {
            f16x8 ah = *(const f16x8*)&R1[FR(ks, lane)];
            f16x8 al = *(const f16x8*)&R1[FR(8 + ks, lane)];
            a0 = mfma16(ah, omf[0][ks], a0);
            a0 = mfma16(ah, omf[1][ks], a0);
            a0 = mfma16(al, omf[0][ks], a0);
        }
        __syncthreads();   // R1 consumers done -> restage as V; write Kp to R2

        stage_BV(V + ((size_t)b*NN + t0) * DVV, R1);
        #pragma unroll
        for (int r = 0; r < 16; ++r) {
            int tok = rowf(r, q);
            float hh = hs[tok] + kmaxv;
            float mm = msk[tok] * INV_SQRT_M;
            float kp = (__expf(a0[r] - hh) + 1e-4f) * mm;
            ksa += kp;
            int ts = tok >> 4, qq = (tok >> 3) & 1, j = tok & 7;
            _Float16 hv = (_Float16)kp;
            R2[FR(w*2 + ts, qq*32 + i) + j] = hv;
            R2[FR(8 + w*2 + ts, qq*32 + i) + j] = (_Float16)(kp - (float)hv);
        }
        __syncthreads();

        f16x8 ah2[2], al2[2];
        #pragma unroll
        for (int ts = 0; ts < 2; ++ts) {
            ah2[ts] = *(const f16x8*)&R2[FR(w*2 + ts, lane)];
            al2[ts] = *(const f16x8*)&R2[FR(8 + w*2 + ts, lane)];
        }
        #pragma unroll
        for (int vt = 0; vt < 4; ++vt) {
            #pragma unroll
            for (int ts = 0; ts < 2; ++ts) {
                f16x8 bh = *(const f16x8*)&R1[FR(vt*2 + ts, lane)];
                f16x8 bl = *(const f16x8*)&R1[FR(8 + vt*2 + ts, lane)];
                kvacc[vt] = mfma16(ah2[ts], bh, kvacc[vt]);
                kvacc[vt] = mfma16(ah2[ts], bl, kvacc[vt]);
                kvacc[vt] = mfma16(al2[ts], bh, kvacc[vt]);
            }
        }
    }

    float* dst = pkv + ((size_t)(b * PP + p) << 15);
    #pragma unroll
    for (int vt = 0; vt < 4; ++vt)
        #pragma unroll
        for (int r = 0; r < 16; ++r) {
            int feat = nt*32 + rowf(r, q);
            dst[feat * DVV + vt*32 + i] = kvacc[vt][r];
        }
    {
        float s = ksa + __shfl_xor(ksa, 32, 64);
        if (q == 0) pks[(size_t)(b * PP + p) * MM + nt*32 + i] = s;
    }
}

// ---------------------------------------------------------------------------
// reduce: sum P partials -> ksum fp32 + KV as hi/lo f16 B-frags (global)
// ---------------------------------------------------------------------------
__global__ __launch_bounds__(256) void reduce_kernel(const float* __restrict__ pkv,
                                                     const float* __restrict__ pks,
                                                     float* __restrict__ ksum,
                                                     _Float16* __restrict__ kvph,
                                                     _Float16* __restrict__ kvpl) {
    const int b = blockIdx.y;
    int g = blockIdx.x * 256 + threadIdx.x;     // 0..32767
    float s = 0.f;
    for (int p = 0; p < PP; ++p) s += pkv[((size_t)(b * PP + p) << 15) + g];
    int f = g >> 7, v = g & 127;
    int vt = v >> 5, iv = v & 31, fs = f >> 4, qq = (f >> 3) & 1, j = f & 7;
    size_t idx = (size_t)b * 32768 + (size_t)((vt*16 + fs)*64 + qq*32 + iv)*8 + j;
    _Float16 h = (_Float16)s;
    kvph[idx] = h;
    kvpl[idx] = (_Float16)(s - (float)h);
    if (blockIdx.x == 0) {
        float ss = 0.f;
        for (int p = 0; p < PP; ++p) ss += pks[(size_t)(b * PP + p) * MM + g];
        ksum[b * MM + g] = ss;
    }
}

// ---------------------------------------------------------------------------
// out: U_Q -> per-token max -> Qp frags -> Out = Qp@KV (MFMA), norm via MFMA
// grid.x = 64 (4 chunks/block) -> 2 blocks/CU for latency overlap
// ---------------------------------------------------------------------------
__global__ __launch_bounds__(256, 2) void out_kernel(const float* __restrict__ Q,
                                                     const float* __restrict__ mask,
                                                     const _Float16* __restrict__ omh,
                                                     const _Float16* __restrict__ oml,
                                                     const float* __restrict__ ksum,
                                                     const _Float16* __restrict__ kvph,
                                                     const _Float16* __restrict__ kvpl,
                                                     float* __restrict__ out) {
    __shared__ __align__(16) _Float16 R1[16 * 520];
    __shared__ __align__(16) _Float16 R2[32 * 520];
    __shared__ float hs[32], msk[32], wmax[4][32], norms[32];
    const int b = blockIdx.y;
    const int tid = threadIdx.x, w = tid >> 6, lane = tid & 63;
    const int i = tid & 31, q = (tid >> 5) & 1;

    f16x8 omf[2][2][8];
    #pragma unroll
    for (int n = 0; n < 2; ++n)
        #pragma unroll
        for (int k = 0; k < 8; ++k) {
            omf[0][n][k] = ((const f16x8*)omh)[((2*w + n)*8 + k)*64 + lane];
            omf[1][n][k] = ((const f16x8*)oml)[((2*w + n)*8 + k)*64 + lane];
        }
    f16x8 bfh[16], bfl[16];   // KV B-frags for this wave's vt=w
    #pragma unroll
    for (int fs = 0; fs < 16; ++fs) {
        bfh[fs] = ((const f16x8*)kvph)[(size_t)b * 4096 + (w*16 + fs)*64 + lane];
        bfl[fs] = ((const f16x8*)kvpl)[(size_t)b * 4096 + (w*16 + fs)*64 + lane];
    }
    f16x8 bnh[4], bnl[4];     // Ksum column frags, fsteps w*4..w*4+3
    #pragma unroll
    for (int u = 0; u < 4; ++u) {
        f16x8 hh, ll;
        #pragma unroll
        for (int j = 0; j < 8; ++j) { hh[j] = (_Float16)0.f; ll[j] = (_Float16)0.f; }
        if (i == 0) {
            #pragma unroll
            for (int j = 0; j < 8; ++j) {
                float s = ksum[b * MM + (4*w + u)*16 + q*8 + j];
                _Float16 h = (_Float16)s;
                hh[j] = h; ll[j] = (_Float16)(s - (float)h);
            }
        }
        bnh[u] = hh; bnl[u] = ll;
    }

    for (int c = 0; c < 4; ++c) {
        int t0 = (blockIdx.x * 4 + c) * CHUNK;
        __syncthreads();
        stage_A(Q + ((size_t)b*NN + t0) * DD, R1, hs, msk,
                mask + (size_t)b*NN + t0, true);
        if (tid < 32) norms[tid] = 1e-8f;
        __syncthreads();

        f32x16 a0, a1;
        #pragma unroll
        for (int r = 0; r < 16; ++r) { a0[r] = 0.f; a1[r] = 0.f; }
        #pragma unroll
        for (int ks = 0; ks < 8; ++ks) {
            f16x8 ah = *(const f16x8*)&R1[FR(ks, lane)];
            f16x8 al = *(const f16x8*)&R1[FR(8 + ks, lane)];
            a0 = mfma16(ah, omf[0][0][ks], a0);
            a0 = mfma16(ah, omf[1][0][ks], a0);
            a0 = mfma16(al, omf[0][0][ks], a0);
            a1 = mfma16(ah, omf[0][1][ks], a1);
            a1 = mfma16(ah, omf[1][1][ks], a1);
            a1 = mfma16(al, omf[0][1][ks], a1);
        }
        float tm[16];
        #pragma unroll
        for (int r = 0; r < 16; ++r) tm[r] = fmaxf(a0[r], a1[r]);
        #pragma unroll
        for (int off = 1; off < 32; off <<= 1)
            #pragma unroll
            for (int r = 0; r < 16; ++r) tm[r] = fmaxf(tm[r], __shfl_xor(tm[r], off, 64));
        if (i == 0)
            #pragma unroll
            for (int r = 0; r < 16; ++r) wmax[w][rowf(r, q)] = tm[r];
        __syncthreads();

        #pragma unroll
        for (int r = 0; r < 16; ++r) {
            int tok = rowf(r, q);
            float tmax = fmaxf(fmaxf(wmax[0][tok], wmax[1][tok]),
                               fmaxf(wmax[2][tok], wmax[3][tok]));
            float hh = hs[tok] + tmax;
            float mm = msk[tok] * INV_SQRT_M;
            #pragma unroll
            for (int n = 0; n < 2; ++n) {
                float qp = (__expf((n ? a1[r] : a0[r]) - hh) + 1e-4f) * mm;
                int feat = (2*w + n)*32 + i;
                int fstep = feat >> 4, fq = (i >> 3) & 1, fj = i & 7;
                _Float16 h = (_Float16)qp;
                R2[FR(fstep, fq*32 + tok) + fj] = h;
                R2[FR(16 + fstep, fq*32 + tok) + fj] = (_Float16)(qp - (float)h);
            }
        }
        __syncthreads();

        f32x16 oa, na;
        #pragma unroll
        for (int r = 0; r < 16; ++r) { oa[r] = 0.f; na[r] = 0.f; }
        #pragma unroll
        for (int fs = 0; fs < 16; ++fs) {
            f16x8 ah = *(const f16x8*)&R2[FR(fs, lane)];
            f16x8 al = *(const f16x8*)&R2[FR(16 + fs, lane)];
            oa = mfma16(ah, bfh[fs], oa);
            oa = mfma16(ah, bfl[fs], oa);
            oa = mfma16(al, bfh[fs], oa);
        }
        #pragma unroll
        for (int u = 0; u < 4; ++u) {
            f16x8 ah = *(const f16x8*)&R2[FR(4*w + u, lane)];
            f16x8 al = *(const f16x8*)&R2[FR(16 + 4*w + u, lane)];
            na = mfma16(ah, bnh[u], na);
            na = mfma16(ah, bnl[u], na);
            na = mfma16(al, bnh[u], na);
        }
        if (i == 0)
            #pragma unroll
            for (int r = 0; r < 16; ++r) atomicAdd(&norms[rowf(r, q)], na[r]);
        __syncthreads();

        float* ob = out + ((size_t)b*NN + t0) * DVV + w*32 + i;
        #pragma unroll
        for (int r = 0; r < 16; ++r) {
            int tok = rowf(r, q);
            ob[(size_t)tok * DVV] = oa[r] * __builtin_amdgcn_rcpf(norms[tok]);
        }
    }
}

extern "C" void kernel_launch(void* const* d_in, const int* in_sizes, int n_in,
                              void* d_out, int out_size, void* d_ws, size_t ws_size,
                              hipStream_t stream) {
    const float* Q     = (const float*)d_in[0];
    const float* K     = (const float*)d_in[1];
    const float* V     = (const float*)d_in[2];
    const float* mask  = (const float*)d_in[3];
    const float* omega = (const float*)d_in[4];
    float* out = (float*)d_out;

    char* ws = (char*)d_ws;
    _Float16* omh    = (_Float16*)(ws);                       // 64 KB
    _Float16* oml    = (_Float16*)(ws + (64 << 10));          // 64 KB
    unsigned* kmaxord = (unsigned*)(ws + (128 << 10));        // 32 B
    float*    ksum   = (float*)(ws + (132 << 10));            // 8 KB
    float*    pks    = (float*)(ws + (140 << 10));            // 256 KB
    _Float16* kvph   = (_Float16*)(ws + (400 << 10));         // 512 KB
    _Float16* kvpl   = (_Float16*)(ws + (912 << 10));         // 512 KB
    float*    pkv    = (float*)(ws + (2 << 20));              // 32 MB

    pack_kernel<<<16, 256, 0, stream>>>(omega, omh, oml, kmaxord);
    kmax_kernel<<<dim3(64, BB), 256, 0, stream>>>(K, omh, kmaxord);
    kv_kernel<<<dim3(64, BB), 256, 0, stream>>>(K, V, mask, omh, oml, kmaxord, pkv, pks);
    reduce_kernel<<<dim3(128, BB), 256, 0, stream>>>(pkv, pks, ksum, kvph, kvpl);
    out_kernel<<<dim3(64, BB), 256, 0, stream>>>(Q, mask, omh, oml, ksum, kvph, kvpl, out);
}

// Round 2
// 247.073 us; speedup vs baseline: 1.2761x; 1.2761x over previous
//
#include <hip/hip_runtime.h>
#include <math.h>

#define BB 8
#define NN 8192
#define DD 128
#define MM 256
#define DVV 128
#define PP 32        // split-N partial blocks per batch
#define CHUNK 32     // tokens per chunk

#define XSCALE 0.29730177875068026f
#define INV_SQRT_M 0.0625f

typedef _Float16 f16x8 __attribute__((ext_vector_type(8)));
typedef float f32x16 __attribute__((ext_vector_type(16)));

// LDS fragment slab: 64 lanes x 8 halves, stride 520 (16B-aligned, bank-spread)
#define FR(s, l) ((s) * 520 + (l) * 8)

__device__ __forceinline__ unsigned f2ord(float f) {
    unsigned u = __float_as_uint(f);
    return (u & 0x80000000u) ? ~u : (u | 0x80000000u);
}
__device__ __forceinline__ float ord2f(unsigned u) {
    return (u & 0x80000000u) ? __uint_as_float(u & 0x7fffffffu) : __uint_as_float(~u);
}
__device__ __forceinline__ f32x16 mfma16(f16x8 a, f16x8 b, f32x16 c) {
    return __builtin_amdgcn_mfma_f32_32x32x16_f16(a, b, c, 0, 0, 0);
}
__device__ __forceinline__ int rowf(int r, int q) { return (r & 3) + 8 * (r >> 2) + 4 * q; }

// Stage X (A-operand): src row-major [32][128] fp32 -> scaled hi/lo f16 frags in R1.
// Slabs: comp*8 + ks (ks = k/16). Also h (=0.5*sum xs^2) and mask.
__device__ __forceinline__ void stage_A(const float* __restrict__ src,
                                        _Float16* R1, float* hs, float* msk,
                                        const float* __restrict__ mrow, bool do_h) {
    const int tid = threadIdx.x;
    const int t = tid >> 3, ks = tid & 7;
    const float4* s4 = (const float4*)(src + t * DD + ks * 16);
    float x[16];
    #pragma unroll
    for (int u = 0; u < 4; ++u) {
        float4 v = s4[u];
        x[u*4+0] = v.x * XSCALE; x[u*4+1] = v.y * XSCALE;
        x[u*4+2] = v.z * XSCALE; x[u*4+3] = v.w * XSCALE;
    }
    if (do_h) {
        float p = 0.f;
        #pragma unroll
        for (int u = 0; u < 16; ++u) p += x[u] * x[u];
        p += __shfl_xor(p, 1, 64); p += __shfl_xor(p, 2, 64); p += __shfl_xor(p, 4, 64);
        if (ks == 0) { hs[t] = 0.5f * p; msk[t] = mrow[t]; }
    }
    #pragma unroll
    for (int q = 0; q < 2; ++q) {
        f16x8 h8, l8;
        #pragma unroll
        for (int j = 0; j < 8; ++j) {
            float xv = x[q*8 + j];
            _Float16 h = (_Float16)xv;
            h8[j] = h; l8[j] = (_Float16)(xv - (float)h);
        }
        *(f16x8*)&R1[FR(0*8 + ks, q*32 + t)] = h8;
        *(f16x8*)&R1[FR(1*8 + ks, q*32 + t)] = l8;
    }
}

// Stage V (B-operand): src [32 rows=k][128 cols=n] fp32 -> hi/lo frags in R1.
// Slabs: (comp*4 + vt)*2 + tstep.
__device__ __forceinline__ void stage_BV(const float* __restrict__ src, _Float16* R1) {
    const int tid = threadIdx.x;
    const int t = tid >> 3, c0 = (tid & 7) * 16;
    const int ts = t >> 4, qq = (t >> 3) & 1, j = t & 7;
    const float4* s4 = (const float4*)(src + t * DVV + c0);
    #pragma unroll
    for (int u = 0; u < 4; ++u) {
        float4 v = s4[u];
        float vv[4] = {v.x, v.y, v.z, v.w};
        #pragma unroll
        for (int e = 0; e < 4; ++e) {
            int c = c0 + u*4 + e;
            int vt = c >> 5, iv = c & 31;
            _Float16 h = (_Float16)vv[e];
            R1[FR((0*4 + vt)*2 + ts, qq*32 + iv) + j] = h;
            R1[FR((1*4 + vt)*2 + ts, qq*32 + iv) + j] = (_Float16)(vv[e] - (float)h);
        }
    }
}

// ---------------------------------------------------------------------------
// pack: omega -> B-frag layout hi/lo f16 in ws; init kmaxord
// ---------------------------------------------------------------------------
__global__ __launch_bounds__(256) void pack_kernel(const float* __restrict__ omega,
                                                   _Float16* __restrict__ omh,
                                                   _Float16* __restrict__ oml,
                                                   unsigned* __restrict__ kmaxord) {
    int g = blockIdx.x * 256 + threadIdx.x;    // 0..4095
    if (g < BB) kmaxord[g] = f2ord(-INFINITY);
    int lane = g & 63, ks = (g >> 6) & 7, nt = g >> 9;
    int q = lane >> 5, i = lane & 31;
    f16x8 h8, l8;
    #pragma unroll
    for (int j = 0; j < 8; ++j) {
        float w = omega[(size_t)(ks*16 + q*8 + j) * MM + nt*32 + i];
        _Float16 h = (_Float16)w;
        h8[j] = h; l8[j] = (_Float16)(w - (float)h);
    }
    ((f16x8*)omh)[g] = h8;
    ((f16x8*)oml)[g] = l8;
}

// ---------------------------------------------------------------------------
// kmax: per-batch max of U_K (hi*hi only -- mx error cancels in the ratio)
// grid.x = 64 (4 chunks/block); plain bounds -> natural VGPR, 2 blocks/CU
// ---------------------------------------------------------------------------
__global__ __launch_bounds__(256) void kmax_kernel(const float* __restrict__ K,
                                                   const _Float16* __restrict__ omh,
                                                   unsigned* __restrict__ kmaxord) {
    __shared__ __align__(16) _Float16 R1[16 * 520];
    __shared__ float wred[4];
    const int b = blockIdx.y;
    const int tid = threadIdx.x, w = tid >> 6, lane = tid & 63;

    f16x8 om[2][8];
    #pragma unroll
    for (int n = 0; n < 2; ++n)
        #pragma unroll
        for (int k = 0; k < 8; ++k)
            om[n][k] = ((const f16x8*)omh)[((2*w + n)*8 + k)*64 + lane];

    float mx = -INFINITY;
    for (int c = 0; c < 4; ++c) {
        int t0 = (blockIdx.x * 4 + c) * CHUNK;
        __syncthreads();
        stage_A(K + ((size_t)b*NN + t0) * DD, R1, nullptr, nullptr, nullptr, false);
        __syncthreads();
        f32x16 a0, a1;
        #pragma unroll
        for (int r = 0; r < 16; ++r) { a0[r] = 0.f; a1[r] = 0.f; }
        #pragma unroll
        for (int ks = 0; ks < 8; ++ks) {
            f16x8 ah = *(const f16x8*)&R1[FR(ks, lane)];
            a0 = mfma16(ah, om[0][ks], a0);
            a1 = mfma16(ah, om[1][ks], a1);
        }
        #pragma unroll
        for (int r = 0; r < 16; ++r) mx = fmaxf(mx, fmaxf(a0[r], a1[r]));
    }
    #pragma unroll
    for (int off = 1; off < 64; off <<= 1) mx = fmaxf(mx, __shfl_xor(mx, off, 64));
    if (lane == 0) wred[w] = mx;
    __syncthreads();
    if (tid == 0)
        atomicMax(kmaxord + b,
                  f2ord(fmaxf(fmaxf(wred[0], wred[1]), fmaxf(wred[2], wred[3]))));
}

// ---------------------------------------------------------------------------
// kv: U_K (3-mfma split) -> Kp -> LDS transpose -> KV = Kp^T V (3-mfma split)
// Feature-split: 2 blocks per p-slot, each owns 128 of 256 features.
//  -> 512 blocks; plain bounds (no VGPR force -> no spill), 2 blocks/CU
//  (p,h) pairs share bx%8 so the duplicate K/V chunk read hits the same XCD L2.
// ---------------------------------------------------------------------------
__global__ __launch_bounds__(256) void kv_kernel(const float* __restrict__ K,
                                                 const float* __restrict__ V,
                                                 const float* __restrict__ mask,
                                                 const _Float16* __restrict__ omh,
                                                 const _Float16* __restrict__ oml,
                                                 const unsigned* __restrict__ kmaxord,
                                                 float* __restrict__ pkv,
                                                 float* __restrict__ pks) {
    __shared__ __align__(16) _Float16 R1[16 * 520];
    __shared__ __align__(16) _Float16 R2[16 * 520];
    __shared__ float hs[32], msk[32];
    const int b = blockIdx.y, bx = blockIdx.x;
    const int rest = bx >> 3;
    const int h = rest & 1;                      // feature half 0/1
    const int p = (rest >> 1) * 8 + (bx & 7);    // N-split slot 0..31
    const int tid = threadIdx.x, w = tid >> 6, lane = tid & 63;
    const int i = tid & 31, q = (tid >> 5) & 1;
    const int nt = h * 4 + w;                    // this wave's 32-feature block (0..7)
    const float kmaxv = ord2f(kmaxord[b]);

    f16x8 omf[2][8];   // [comp][ks]
    #pragma unroll
    for (int k = 0; k < 8; ++k) {
        omf[0][k] = ((const f16x8*)omh)[(nt*8 + k)*64 + lane];
        omf[1][k] = ((const f16x8*)oml)[(nt*8 + k)*64 + lane];
    }

    f32x16 kvacc[4];
    #pragma unroll
    for (int vt = 0; vt < 4; ++vt)
        #pragma unroll
        for (int r = 0; r < 16; ++r) kvacc[vt][r] = 0.f;
    float ksa = 0.f;

    for (int c = 0; c < 8; ++c) {
        int t0 = (p * 8 + c) * CHUNK;
        __syncthreads();
        stage_A(K + ((size_t)b*NN + t0) * DD, R1, hs, msk,
                mask + (size_t)b*NN + t0, true);
        __syncthreads();

        f32x16 a0;
        #pragma unroll
        for (int r = 0; r < 16; ++r) a0[r] = 0.f;
        #pragma unroll
        for (int ks = 0; ks < 8; ++ks) {
            f16x8 ah = *(const f16x8*)&R1[FR(ks, lane)];
            f16x8 al = *(const f16x8*)&R1[FR(8 + ks, lane)];
            a0 = mfma16(ah, omf[0][ks], a0);
            a0 = mfma16(ah, omf[1][ks], a0);
            a0 = mfma16(al, omf[0][ks], a0);
        }
        __syncthreads();   // R1 consumers done -> restage as V; write Kp to R2

        stage_BV(V + ((size_t)b*NN + t0) * DVV, R1);
        #pragma unroll
        for (int r = 0; r < 16; ++r) {
            int tok = rowf(r, q);
            float hh = hs[tok] + kmaxv;
            float mm = msk[tok] * INV_SQRT_M;
            float kp = (__expf(a0[r] - hh) + 1e-4f) * mm;
            ksa += kp;
            int ts = tok >> 4, qq = (tok >> 3) & 1, j = tok & 7;
            _Float16 hv = (_Float16)kp;
            R2[FR(w*2 + ts, qq*32 + i) + j] = hv;
            R2[FR(8 + w*2 + ts, qq*32 + i) + j] = (_Float16)(kp - (float)hv);
        }
        __syncthreads();

        f16x8 ah2[2], al2[2];
        #pragma unroll
        for (int ts = 0; ts < 2; ++ts) {
            ah2[ts] = *(const f16x8*)&R2[FR(w*2 + ts, lane)];
            al2[ts] = *(const f16x8*)&R2[FR(8 + w*2 + ts, lane)];
        }
        #pragma unroll
        for (int vt = 0; vt < 4; ++vt) {
            #pragma unroll
            for (int ts = 0; ts < 2; ++ts) {
                f16x8 bh = *(const f16x8*)&R1[FR(vt*2 + ts, lane)];
                f16x8 bl = *(const f16x8*)&R1[FR(8 + vt*2 + ts, lane)];
                kvacc[vt] = mfma16(ah2[ts], bh, kvacc[vt]);
                kvacc[vt] = mfma16(ah2[ts], bl, kvacc[vt]);
                kvacc[vt] = mfma16(al2[ts], bh, kvacc[vt]);
            }
        }
    }

    float* dst = pkv + ((size_t)(b * PP + p) << 15);
    #pragma unroll
    for (int vt = 0; vt < 4; ++vt)
        #pragma unroll
        for (int r = 0; r < 16; ++r) {
            int feat = nt*32 + rowf(r, q);
            dst[feat * DVV + vt*32 + i] = kvacc[vt][r];
        }
    {
        float s = ksa + __shfl_xor(ksa, 32, 64);
        if (q == 0) pks[(size_t)(b * PP + p) * MM + nt*32 + i] = s;
    }
}

// ---------------------------------------------------------------------------
// reduce: sum P partials -> ksum fp32 + KV as hi/lo f16 B-frags (global)
// ---------------------------------------------------------------------------
__global__ __launch_bounds__(256) void reduce_kernel(const float* __restrict__ pkv,
                                                     const float* __restrict__ pks,
                                                     float* __restrict__ ksum,
                                                     _Float16* __restrict__ kvph,
                                                     _Float16* __restrict__ kvpl) {
    const int b = blockIdx.y;
    int g = blockIdx.x * 256 + threadIdx.x;     // 0..32767
    float s = 0.f;
    for (int p = 0; p < PP; ++p) s += pkv[((size_t)(b * PP + p) << 15) + g];
    int f = g >> 7, v = g & 127;
    int vt = v >> 5, iv = v & 31, fs = f >> 4, qq = (f >> 3) & 1, j = f & 7;
    size_t idx = (size_t)b * 32768 + (size_t)((vt*16 + fs)*64 + qq*32 + iv)*8 + j;
    _Float16 h = (_Float16)s;
    kvph[idx] = h;
    kvpl[idx] = (_Float16)(s - (float)h);
    if (blockIdx.x == 0) {
        float ss = 0.f;
        for (int p = 0; p < PP; ++p) ss += pks[(size_t)(b * PP + p) * MM + g];
        ksum[b * MM + g] = ss;
    }
}

// ---------------------------------------------------------------------------
// out: U_Q -> per-token max -> Qp frags -> Out = Qp@KV (MFMA), norm via MFMA
// grid.x = 64 (4 chunks/block); plain bounds -> natural ~240 VGPR (no spill),
// 2 blocks/CU from VGPR 240<=256 + LDS 50KB*2<=160KB.
// ---------------------------------------------------------------------------
__global__ __launch_bounds__(256) void out_kernel(const float* __restrict__ Q,
                                                  const float* __restrict__ mask,
                                                  const _Float16* __restrict__ omh,
                                                  const _Float16* __restrict__ oml,
                                                  const float* __restrict__ ksum,
                                                  const _Float16* __restrict__ kvph,
                                                  const _Float16* __restrict__ kvpl,
                                                  float* __restrict__ out) {
    __shared__ __align__(16) _Float16 R1[16 * 520];
    __shared__ __align__(16) _Float16 R2[32 * 520];
    __shared__ float hs[32], msk[32], wmax[4][32], norms[32];
    const int b = blockIdx.y;
    const int tid = threadIdx.x, w = tid >> 6, lane = tid & 63;
    const int i = tid & 31, q = (tid >> 5) & 1;

    f16x8 omf[2][2][8];
    #pragma unroll
    for (int n = 0; n < 2; ++n)
        #pragma unroll
        for (int k = 0; k < 8; ++k) {
            omf[0][n][k] = ((const f16x8*)omh)[((2*w + n)*8 + k)*64 + lane];
            omf[1][n][k] = ((const f16x8*)oml)[((2*w + n)*8 + k)*64 + lane];
        }
    f16x8 bfh[16], bfl[16];   // KV B-frags for this wave's vt=w
    #pragma unroll
    for (int fs = 0; fs < 16; ++fs) {
        bfh[fs] = ((const f16x8*)kvph)[(size_t)b * 4096 + (w*16 + fs)*64 + lane];
        bfl[fs] = ((const f16x8*)kvpl)[(size_t)b * 4096 + (w*16 + fs)*64 + lane];
    }
    f16x8 bnh[4], bnl[4];     // Ksum column frags, fsteps w*4..w*4+3
    #pragma unroll
    for (int u = 0; u < 4; ++u) {
        f16x8 hh, ll;
        #pragma unroll
        for (int j = 0; j < 8; ++j) { hh[j] = (_Float16)0.f; ll[j] = (_Float16)0.f; }
        if (i == 0) {
            #pragma unroll
            for (int j = 0; j < 8; ++j) {
                float s = ksum[b * MM + (4*w + u)*16 + q*8 + j];
                _Float16 h = (_Float16)s;
                hh[j] = h; ll[j] = (_Float16)(s - (float)h);
            }
        }
        bnh[u] = hh; bnl[u] = ll;
    }

    for (int c = 0; c < 4; ++c) {
        int t0 = (blockIdx.x * 4 + c) * CHUNK;
        __syncthreads();
        stage_A(Q + ((size_t)b*NN + t0) * DD, R1, hs, msk,
                mask + (size_t)b*NN + t0, true);
        if (tid < 32) norms[tid] = 1e-8f;
        __syncthreads();

        f32x16 a0, a1;
        #pragma unroll
        for (int r = 0; r < 16; ++r) { a0[r] = 0.f; a1[r] = 0.f; }
        #pragma unroll
        for (int ks = 0; ks < 8; ++ks) {
            f16x8 ah = *(const f16x8*)&R1[FR(ks, lane)];
            f16x8 al = *(const f16x8*)&R1[FR(8 + ks, lane)];
            a0 = mfma16(ah, omf[0][0][ks], a0);
            a0 = mfma16(ah, omf[1][0][ks], a0);
            a0 = mfma16(al, omf[0][0][ks], a0);
            a1 = mfma16(ah, omf[0][1][ks], a1);
            a1 = mfma16(ah, omf[1][1][ks], a1);
            a1 = mfma16(al, omf[0][1][ks], a1);
        }
        float tm[16];
        #pragma unroll
        for (int r = 0; r < 16; ++r) tm[r] = fmaxf(a0[r], a1[r]);
        #pragma unroll
        for (int off = 1; off < 32; off <<= 1)
            #pragma unroll
            for (int r = 0; r < 16; ++r) tm[r] = fmaxf(tm[r], __shfl_xor(tm[r], off, 64));
        if (i == 0)
            #pragma unroll
            for (int r = 0; r < 16; ++r) wmax[w][rowf(r, q)] = tm[r];
        __syncthreads();

        #pragma unroll
        for (int r = 0; r < 16; ++r) {
            int tok = rowf(r, q);
            float tmax = fmaxf(fmaxf(wmax[0][tok], wmax[1][tok]),
                               fmaxf(wmax[2][tok], wmax[3][tok]));
            float hh = hs[tok] + tmax;
            float mm = msk[tok] * INV_SQRT_M;
            #pragma unroll
            for (int n = 0; n < 2; ++n) {
                float qp = (__expf((n ? a1[r] : a0[r]) - hh) + 1e-4f) * mm;
                int feat = (2*w + n)*32 + i;
                int fstep = feat >> 4, fq = (i >> 3) & 1, fj = i & 7;
                _Float16 h = (_Float16)qp;
                R2[FR(fstep, fq*32 + tok) + fj] = h;
                R2[FR(16 + fstep, fq*32 + tok) + fj] = (_Float16)(qp - (float)h);
            }
        }
        __syncthreads();

        f32x16 oa, na;
        #pragma unroll
        for (int r = 0; r < 16; ++r) { oa[r] = 0.f; na[r] = 0.f; }
        #pragma unroll
        for (int fs = 0; fs < 16; ++fs) {
            f16x8 ah = *(const f16x8*)&R2[FR(fs, lane)];
            f16x8 al = *(const f16x8*)&R2[FR(16 + fs, lane)];
            oa = mfma16(ah, bfh[fs], oa);
            oa = mfma16(ah, bfl[fs], oa);
            oa = mfma16(al, bfh[fs], oa);
        }
        #pragma unroll
        for (int u = 0; u < 4; ++u) {
            f16x8 ah = *(const f16x8*)&R2[FR(4*w + u, lane)];
            f16x8 al = *(const f16x8*)&R2[FR(16 + 4*w + u, lane)];
            na = mfma16(ah, bnh[u], na);
            na = mfma16(ah, bnl[u], na);
            na = mfma16(al, bnh[u], na);
        }
        if (i == 0)
            #pragma unroll
            for (int r = 0; r < 16; ++r) atomicAdd(&norms[rowf(r, q)], na[r]);
        __syncthreads();

        float* ob = out + ((size_t)b*NN + t0) * DVV + w*32 + i;
        #pragma unroll
        for (int r = 0; r < 16; ++r) {
            int tok = rowf(r, q);
            ob[(size_t)tok * DVV] = oa[r] * __builtin_amdgcn_rcpf(norms[tok]);
        }
    }
}

extern "C" void kernel_launch(void* const* d_in, const int* in_sizes, int n_in,
                              void* d_out, int out_size, void* d_ws, size_t ws_size,
                              hipStream_t stream) {
    const float* Q     = (const float*)d_in[0];
    const float* K     = (const float*)d_in[1];
    const float* V     = (const float*)d_in[2];
    const float* mask  = (const float*)d_in[3];
    const float* omega = (const float*)d_in[4];
    float* out = (float*)d_out;

    char* ws = (char*)d_ws;
    _Float16* omh    = (_Float16*)(ws);                       // 64 KB
    _Float16* oml    = (_Float16*)(ws + (64 << 10));          // 64 KB
    unsigned* kmaxord = (unsigned*)(ws + (128 << 10));        // 32 B
    float*    ksum   = (float*)(ws + (132 << 10));            // 8 KB
    float*    pks    = (float*)(ws + (140 << 10));            // 256 KB
    _Float16* kvph   = (_Float16*)(ws + (400 << 10));         // 512 KB
    _Float16* kvpl   = (_Float16*)(ws + (912 << 10));         // 512 KB
    float*    pkv    = (float*)(ws + (2 << 20));              // 32 MB

    pack_kernel<<<16, 256, 0, stream>>>(omega, omh, oml, kmaxord);
    kmax_kernel<<<dim3(64, BB), 256, 0, stream>>>(K, omh, kmaxord);
    kv_kernel<<<dim3(64, BB), 256, 0, stream>>>(K, V, mask, omh, oml, kmaxord, pkv, pks);
    reduce_kernel<<<dim3(128, BB), 256, 0, stream>>>(pkv, pks, ksum, kvph, kvpl);
    out_kernel<<<dim3(64, BB), 256, 0, stream>>>(Q, mask, omh, oml, ksum, kvph, kvpl, out);
}

// Round 3
// 241.076 us; speedup vs baseline: 1.3079x; 1.0249x over previous
//
#include <hip/hip_runtime.h>
#include <math.h>

#define BB 8
#define NN 8192
#define DD 128
#define MM 256
#define DVV 128
#define PP 32        // split-N partial blocks per batch
#define CHUNK 32     // tokens per chunk

#define XSCALE 0.29730177875068026f
#define INV_SQRT_M 0.0625f

typedef _Float16 f16x8 __attribute__((ext_vector_type(8)));
typedef float f32x16 __attribute__((ext_vector_type(16)));

// LDS fragment slab: 64 lanes x 8 halves, stride 520 (16B-aligned, bank-spread)
#define FR(s, l) ((s) * 520 + (l) * 8)

__device__ __forceinline__ unsigned f2ord(float f) {
    unsigned u = __float_as_uint(f);
    return (u & 0x80000000u) ? ~u : (u | 0x80000000u);
}
__device__ __forceinline__ float ord2f(unsigned u) {
    return (u & 0x80000000u) ? __uint_as_float(u & 0x7fffffffu) : __uint_as_float(~u);
}
__device__ __forceinline__ f32x16 mfma16(f16x8 a, f16x8 b, f32x16 c) {
    return __builtin_amdgcn_mfma_f32_32x32x16_f16(a, b, c, 0, 0, 0);
}
__device__ __forceinline__ int rowf(int r, int q) { return (r & 3) + 8 * (r >> 2) + 4 * q; }

// Stage X (A-operand): src row-major [32][128] fp32 -> scaled hi/lo f16 frags in R1.
__device__ __forceinline__ void stage_A(const float* __restrict__ src,
                                        _Float16* R1, float* hs, float* msk,
                                        const float* __restrict__ mrow, bool do_h) {
    const int tid = threadIdx.x;
    const int t = tid >> 3, ks = tid & 7;
    const float4* s4 = (const float4*)(src + t * DD + ks * 16);
    float x[16];
    #pragma unroll
    for (int u = 0; u < 4; ++u) {
        float4 v = s4[u];
        x[u*4+0] = v.x * XSCALE; x[u*4+1] = v.y * XSCALE;
        x[u*4+2] = v.z * XSCALE; x[u*4+3] = v.w * XSCALE;
    }
    if (do_h) {
        float p = 0.f;
        #pragma unroll
        for (int u = 0; u < 16; ++u) p += x[u] * x[u];
        p += __shfl_xor(p, 1, 64); p += __shfl_xor(p, 2, 64); p += __shfl_xor(p, 4, 64);
        if (ks == 0) { hs[t] = 0.5f * p; msk[t] = mrow[t]; }
    }
    #pragma unroll
    for (int q = 0; q < 2; ++q) {
        f16x8 h8, l8;
        #pragma unroll
        for (int j = 0; j < 8; ++j) {
            float xv = x[q*8 + j];
            _Float16 h = (_Float16)xv;
            h8[j] = h; l8[j] = (_Float16)(xv - (float)h);
        }
        *(f16x8*)&R1[FR(0*8 + ks, q*32 + t)] = h8;
        *(f16x8*)&R1[FR(1*8 + ks, q*32 + t)] = l8;
    }
}

// Stage V (B-operand): src [32 rows=k][128 cols=n] fp32 -> hi/lo frags in R1.
__device__ __forceinline__ void stage_BV(const float* __restrict__ src, _Float16* R1) {
    const int tid = threadIdx.x;
    const int t = tid >> 3, c0 = (tid & 7) * 16;
    const int ts = t >> 4, qq = (t >> 3) & 1, j = t & 7;
    const float4* s4 = (const float4*)(src + t * DVV + c0);
    #pragma unroll
    for (int u = 0; u < 4; ++u) {
        float4 v = s4[u];
        float vv[4] = {v.x, v.y, v.z, v.w};
        #pragma unroll
        for (int e = 0; e < 4; ++e) {
            int c = c0 + u*4 + e;
            int vt = c >> 5, iv = c & 31;
            _Float16 h = (_Float16)vv[e];
            R1[FR((0*4 + vt)*2 + ts, qq*32 + iv) + j] = h;
            R1[FR((1*4 + vt)*2 + ts, qq*32 + iv) + j] = (_Float16)(vv[e] - (float)h);
        }
    }
}

// ---------------------------------------------------------------------------
// pack: omega -> B-frag layout hi/lo f16 in ws; init kmaxord
// ---------------------------------------------------------------------------
__global__ __launch_bounds__(256) void pack_kernel(const float* __restrict__ omega,
                                                   _Float16* __restrict__ omh,
                                                   _Float16* __restrict__ oml,
                                                   unsigned* __restrict__ kmaxord) {
    int g = blockIdx.x * 256 + threadIdx.x;    // 0..4095
    if (g < BB) kmaxord[g] = f2ord(-INFINITY);
    int lane = g & 63, ks = (g >> 6) & 7, nt = g >> 9;
    int q = lane >> 5, i = lane & 31;
    f16x8 h8, l8;
    #pragma unroll
    for (int j = 0; j < 8; ++j) {
        float w = omega[(size_t)(ks*16 + q*8 + j) * MM + nt*32 + i];
        _Float16 h = (_Float16)w;
        h8[j] = h; l8[j] = (_Float16)(w - (float)h);
    }
    ((f16x8*)omh)[g] = h8;
    ((f16x8*)oml)[g] = l8;
}

// ---------------------------------------------------------------------------
// kmax: per-batch max of U_K (hi*hi only -- mx error cancels in the ratio)
// om frags STREAMED from L2 (not register-resident) -> low VGPR, multi-wave/SIMD
// ---------------------------------------------------------------------------
__global__ __launch_bounds__(256) void kmax_kernel(const float* __restrict__ K,
                                                   const _Float16* __restrict__ omh,
                                                   unsigned* __restrict__ kmaxord) {
    __shared__ __align__(16) _Float16 R1[16 * 520];
    __shared__ float wred[4];
    const int b = blockIdx.y;
    const int tid = threadIdx.x, w = tid >> 6, lane = tid & 63;
    const int w2 = 2 * w;
    const f16x8* OH = (const f16x8*)omh;

    float mx = -INFINITY;
    #pragma unroll 1
    for (int c = 0; c < 4; ++c) {
        int t0 = (blockIdx.x * 4 + c) * CHUNK;
        __syncthreads();
        stage_A(K + ((size_t)b*NN + t0) * DD, R1, nullptr, nullptr, nullptr, false);
        __syncthreads();
        f32x16 a0, a1;
        #pragma unroll
        for (int r = 0; r < 16; ++r) { a0[r] = 0.f; a1[r] = 0.f; }
        f16x8 X0 = OH[(w2*8 + 0)*64 + lane];
        f16x8 X1 = OH[((w2+1)*8 + 0)*64 + lane];
        #pragma unroll 1
        for (int ks = 0; ks < 8; ks += 2) {
            f16x8 Y0 = OH[(w2*8 + ks + 1)*64 + lane];
            f16x8 Y1 = OH[((w2+1)*8 + ks + 1)*64 + lane];
            f16x8 ah = *(const f16x8*)&R1[FR(ks, lane)];
            a0 = mfma16(ah, X0, a0);
            a1 = mfma16(ah, X1, a1);
            int k2 = (ks + 2) & 7;
            X0 = OH[(w2*8 + k2)*64 + lane];
            X1 = OH[((w2+1)*8 + k2)*64 + lane];
            f16x8 ah2 = *(const f16x8*)&R1[FR(ks + 1, lane)];
            a0 = mfma16(ah2, Y0, a0);
            a1 = mfma16(ah2, Y1, a1);
        }
        #pragma unroll
        for (int r = 0; r < 16; ++r) mx = fmaxf(mx, fmaxf(a0[r], a1[r]));
    }
    #pragma unroll
    for (int off = 1; off < 64; off <<= 1) mx = fmaxf(mx, __shfl_xor(mx, off, 64));
    if (lane == 0) wred[w] = mx;
    __syncthreads();
    if (tid == 0)
        atomicMax(kmaxord + b,
                  f2ord(fmaxf(fmaxf(wred[0], wred[1]), fmaxf(wred[2], wred[3]))));
}

// ---------------------------------------------------------------------------
// kv: U_K (3-mfma split) -> Kp -> LDS transpose -> KV = Kp^T V (3-mfma split)
// Feature-split (2 blocks per p-slot); om frags STREAMED from L2 so only
// kvacc (64 AGPR) stays resident -> total regs/wave aims <=256 -> 2 waves/SIMD.
// ---------------------------------------------------------------------------
__global__ __launch_bounds__(256) void kv_kernel(const float* __restrict__ K,
                                                 const float* __restrict__ V,
                                                 const float* __restrict__ mask,
                                                 const _Float16* __restrict__ omh,
                                                 const _Float16* __restrict__ oml,
                                                 const unsigned* __restrict__ kmaxord,
                                                 float* __restrict__ pkv,
                                                 float* __restrict__ pks) {
    __shared__ __align__(16) _Float16 R1[16 * 520];
    __shared__ __align__(16) _Float16 R2[16 * 520];
    __shared__ float hs[32], msk[32];
    const int b = blockIdx.y, bx = blockIdx.x;
    const int rest = bx >> 3;
    const int h = rest & 1;                      // feature half 0/1
    const int p = (rest >> 1) * 8 + (bx & 7);    // N-split slot 0..31
    const int tid = threadIdx.x, w = tid >> 6, lane = tid & 63;
    const int i = tid & 31, q = (tid >> 5) & 1;
    const int nt = h * 4 + w;                    // this wave's 32-feature block (0..7)
    const float kmaxv = ord2f(kmaxord[b]);
    const f16x8* OH = (const f16x8*)omh;
    const f16x8* OL = (const f16x8*)oml;

    f32x16 kvacc[4];
    #pragma unroll
    for (int vt = 0; vt < 4; ++vt)
        #pragma unroll
        for (int r = 0; r < 16; ++r) kvacc[vt][r] = 0.f;
    float ksa = 0.f;

    #pragma unroll 1
    for (int c = 0; c < 8; ++c) {
        int t0 = (p * 8 + c) * CHUNK;
        __syncthreads();
        stage_A(K + ((size_t)b*NN + t0) * DD, R1, hs, msk,
                mask + (size_t)b*NN + t0, true);
        __syncthreads();

        f32x16 a0;
        #pragma unroll
        for (int r = 0; r < 16; ++r) a0[r] = 0.f;
        f16x8 Xh = OH[(nt*8 + 0)*64 + lane];
        f16x8 Xl = OL[(nt*8 + 0)*64 + lane];
        #pragma unroll 1
        for (int ks = 0; ks < 8; ks += 2) {
            f16x8 Yh = OH[(nt*8 + ks + 1)*64 + lane];
            f16x8 Yl = OL[(nt*8 + ks + 1)*64 + lane];
            f16x8 ah = *(const f16x8*)&R1[FR(ks, lane)];
            f16x8 al = *(const f16x8*)&R1[FR(8 + ks, lane)];
            a0 = mfma16(ah, Xh, a0);
            a0 = mfma16(ah, Xl, a0);
            a0 = mfma16(al, Xh, a0);
            int k2 = (ks + 2) & 7;
            Xh = OH[(nt*8 + k2)*64 + lane];
            Xl = OL[(nt*8 + k2)*64 + lane];
            f16x8 ah2 = *(const f16x8*)&R1[FR(ks + 1, lane)];
            f16x8 al2 = *(const f16x8*)&R1[FR(8 + ks + 1, lane)];
            a0 = mfma16(ah2, Yh, a0);
            a0 = mfma16(ah2, Yl, a0);
            a0 = mfma16(al2, Yh, a0);
        }
        __syncthreads();   // R1 consumers done -> restage as V; write Kp to R2

        stage_BV(V + ((size_t)b*NN + t0) * DVV, R1);
        #pragma unroll
        for (int r = 0; r < 16; ++r) {
            int tok = rowf(r, q);
            float hh = hs[tok] + kmaxv;
            float mm = msk[tok] * INV_SQRT_M;
            float kp = (__expf(a0[r] - hh) + 1e-4f) * mm;
            ksa += kp;
            int ts = tok >> 4, qq = (tok >> 3) & 1, j = tok & 7;
            _Float16 hv = (_Float16)kp;
            R2[FR(w*2 + ts, qq*32 + i) + j] = hv;
            R2[FR(8 + w*2 + ts, qq*32 + i) + j] = (_Float16)(kp - (float)hv);
        }
        __syncthreads();

        f16x8 ah2[2], al2[2];
        #pragma unroll
        for (int ts = 0; ts < 2; ++ts) {
            ah2[ts] = *(const f16x8*)&R2[FR(w*2 + ts, lane)];
            al2[ts] = *(const f16x8*)&R2[FR(8 + w*2 + ts, lane)];
        }
        #pragma unroll
        for (int vt = 0; vt < 4; ++vt) {
            #pragma unroll
            for (int ts = 0; ts < 2; ++ts) {
                f16x8 bh = *(const f16x8*)&R1[FR(vt*2 + ts, lane)];
                f16x8 bl = *(const f16x8*)&R1[FR(8 + vt*2 + ts, lane)];
                kvacc[vt] = mfma16(ah2[ts], bh, kvacc[vt]);
                kvacc[vt] = mfma16(ah2[ts], bl, kvacc[vt]);
                kvacc[vt] = mfma16(al2[ts], bh, kvacc[vt]);
            }
        }
    }

    float* dst = pkv + ((size_t)(b * PP + p) << 15);
    #pragma unroll
    for (int vt = 0; vt < 4; ++vt)
        #pragma unroll
        for (int r = 0; r < 16; ++r) {
            int feat = nt*32 + rowf(r, q);
            dst[feat * DVV + vt*32 + i] = kvacc[vt][r];
        }
    {
        float s = ksa + __shfl_xor(ksa, 32, 64);
        if (q == 0) pks[(size_t)(b * PP + p) * MM + nt*32 + i] = s;
    }
}

// ---------------------------------------------------------------------------
// reduce: sum P partials -> ksum fp32 + KV as hi/lo f16 B-frags (global)
// ---------------------------------------------------------------------------
__global__ __launch_bounds__(256) void reduce_kernel(const float* __restrict__ pkv,
                                                     const float* __restrict__ pks,
                                                     float* __restrict__ ksum,
                                                     _Float16* __restrict__ kvph,
                                                     _Float16* __restrict__ kvpl) {
    const int b = blockIdx.y;
    int g = blockIdx.x * 256 + threadIdx.x;     // 0..32767
    float s = 0.f;
    for (int p = 0; p < PP; ++p) s += pkv[((size_t)(b * PP + p) << 15) + g];
    int f = g >> 7, v = g & 127;
    int vt = v >> 5, iv = v & 31, fs = f >> 4, qq = (f >> 3) & 1, j = f & 7;
    size_t idx = (size_t)b * 32768 + (size_t)((vt*16 + fs)*64 + qq*32 + iv)*8 + j;
    _Float16 h = (_Float16)s;
    kvph[idx] = h;
    kvpl[idx] = (_Float16)(s - (float)h);
    if (blockIdx.x == 0) {
        float ss = 0.f;
        for (int p = 0; p < PP; ++p) ss += pks[(size_t)(b * PP + p) * MM + g];
        ksum[b * MM + g] = ss;
    }
}

// ---------------------------------------------------------------------------
// out: U_Q -> per-token max -> Qp frags -> Out = Qp@KV (MFMA)
// om and KV frags STREAMED from L2 (1-ahead prefetch, manual unroll-2) so no
// 128-reg panels stay resident; norm computed via f32 FMA + shuffle tree
// (replaces 12 MFMAs + 48 regs of bn frags). Target: <=~170 regs/wave ->
// 2-3 waves/SIMD (LDS 50KB caps at 3 blocks/CU).
// ---------------------------------------------------------------------------
__global__ __launch_bounds__(256) void out_kernel(const float* __restrict__ Q,
                                                  const float* __restrict__ mask,
                                                  const _Float16* __restrict__ omh,
                                                  const _Float16* __restrict__ oml,
                                                  const float* __restrict__ ksum,
                                                  const _Float16* __restrict__ kvph,
                                                  const _Float16* __restrict__ kvpl,
                                                  float* __restrict__ out) {
    __shared__ __align__(16) _Float16 R1[16 * 520];
    __shared__ __align__(16) _Float16 R2[32 * 520];
    __shared__ float hs[32], msk[32], wmax[4][32], norms[32];
    const int b = blockIdx.y;
    const int tid = threadIdx.x, w = tid >> 6, lane = tid & 63;
    const int i = tid & 31, q = (tid >> 5) & 1;
    const int w2 = 2 * w;
    const f16x8* OH = (const f16x8*)omh;
    const f16x8* OL = (const f16x8*)oml;
    const f16x8* KH = (const f16x8*)kvph + (size_t)b * 4096 + (w*16)*64 + lane;
    const f16x8* KL = (const f16x8*)kvpl + (size_t)b * 4096 + (w*16)*64 + lane;
    const float nk0 = ksum[b * MM + w2*32 + i];
    const float nk1 = ksum[b * MM + (w2+1)*32 + i];

    #pragma unroll 1
    for (int c = 0; c < 4; ++c) {
        int t0 = (blockIdx.x * 4 + c) * CHUNK;
        __syncthreads();
        stage_A(Q + ((size_t)b*NN + t0) * DD, R1, hs, msk,
                mask + (size_t)b*NN + t0, true);
        if (tid < 32) norms[tid] = 1e-8f;
        __syncthreads();

        // --- U_Q: stream om frags from L2 ---
        f32x16 a0, a1;
        #pragma unroll
        for (int r = 0; r < 16; ++r) { a0[r] = 0.f; a1[r] = 0.f; }
        f16x8 X0h = OH[(w2*8 + 0)*64 + lane], X0l = OL[(w2*8 + 0)*64 + lane];
        f16x8 X1h = OH[((w2+1)*8 + 0)*64 + lane], X1l = OL[((w2+1)*8 + 0)*64 + lane];
        #pragma unroll 1
        for (int ks = 0; ks < 8; ks += 2) {
            f16x8 Y0h = OH[(w2*8 + ks + 1)*64 + lane], Y0l = OL[(w2*8 + ks + 1)*64 + lane];
            f16x8 Y1h = OH[((w2+1)*8 + ks + 1)*64 + lane], Y1l = OL[((w2+1)*8 + ks + 1)*64 + lane];
            f16x8 ah = *(const f16x8*)&R1[FR(ks, lane)];
            f16x8 al = *(const f16x8*)&R1[FR(8 + ks, lane)];
            a0 = mfma16(ah, X0h, a0); a0 = mfma16(ah, X0l, a0); a0 = mfma16(al, X0h, a0);
            a1 = mfma16(ah, X1h, a1); a1 = mfma16(ah, X1l, a1); a1 = mfma16(al, X1h, a1);
            int k2 = (ks + 2) & 7;
            X0h = OH[(w2*8 + k2)*64 + lane]; X0l = OL[(w2*8 + k2)*64 + lane];
            X1h = OH[((w2+1)*8 + k2)*64 + lane]; X1l = OL[((w2+1)*8 + k2)*64 + lane];
            f16x8 ah2 = *(const f16x8*)&R1[FR(ks + 1, lane)];
            f16x8 al2 = *(const f16x8*)&R1[FR(8 + ks + 1, lane)];
            a0 = mfma16(ah2, Y0h, a0); a0 = mfma16(ah2, Y0l, a0); a0 = mfma16(al2, Y0h, a0);
            a1 = mfma16(ah2, Y1h, a1); a1 = mfma16(ah2, Y1l, a1); a1 = mfma16(al2, Y1h, a1);
        }

        // --- per-token max across 256 feats ---
        float tm[16];
        #pragma unroll
        for (int r = 0; r < 16; ++r) tm[r] = fmaxf(a0[r], a1[r]);
        #pragma unroll
        for (int off = 1; off < 32; off <<= 1)
            #pragma unroll
            for (int r = 0; r < 16; ++r) tm[r] = fmaxf(tm[r], __shfl_xor(tm[r], off, 64));
        if (i == 0)
            #pragma unroll
            for (int r = 0; r < 16; ++r) wmax[w][rowf(r, q)] = tm[r];
        __syncthreads();

        // --- Qp = exp(U-h-mx)+eps, write hi/lo frags; norm partial in f32 ---
        float nacc[16];
        #pragma unroll
        for (int r = 0; r < 16; ++r) {
            int tok = rowf(r, q);
            float tmax = fmaxf(fmaxf(wmax[0][tok], wmax[1][tok]),
                               fmaxf(wmax[2][tok], wmax[3][tok]));
            float hh = hs[tok] + tmax;
            float mm = msk[tok] * INV_SQRT_M;
            float qp0 = (__expf(a0[r] - hh) + 1e-4f) * mm;
            float qp1 = (__expf(a1[r] - hh) + 1e-4f) * mm;
            nacc[r] = qp0 * nk0 + qp1 * nk1;
            {
                int feat = w2*32 + i;
                int fstep = feat >> 4, fq = (i >> 3) & 1, fj = i & 7;
                _Float16 hv = (_Float16)qp0;
                R2[FR(fstep, fq*32 + tok) + fj] = hv;
                R2[FR(16 + fstep, fq*32 + tok) + fj] = (_Float16)(qp0 - (float)hv);
            }
            {
                int feat = (w2+1)*32 + i;
                int fstep = feat >> 4, fq = (i >> 3) & 1, fj = i & 7;
                _Float16 hv = (_Float16)qp1;
                R2[FR(fstep, fq*32 + tok) + fj] = hv;
                R2[FR(16 + fstep, fq*32 + tok) + fj] = (_Float16)(qp1 - (float)hv);
            }
        }
        // reduce norm partials over the 32 i-lanes (per half-wave)
        #pragma unroll
        for (int off = 1; off < 32; off <<= 1)
            #pragma unroll
            for (int r = 0; r < 16; ++r) nacc[r] += __shfl_xor(nacc[r], off, 64);
        if (i == 0)
            #pragma unroll
            for (int r = 0; r < 16; ++r) atomicAdd(&norms[rowf(r, q)], nacc[r]);
        __syncthreads();   // R2 frags + norms complete

        // --- Out = Qp @ KV: stream KV frags from L2 ---
        f32x16 oa;
        #pragma unroll
        for (int r = 0; r < 16; ++r) oa[r] = 0.f;
        f16x8 Fh = KH[0], Fl = KL[0];
        #pragma unroll 1
        for (int fs = 0; fs < 16; fs += 2) {
            f16x8 Gh = KH[(fs + 1)*64], Gl = KL[(fs + 1)*64];
            f16x8 ah = *(const f16x8*)&R2[FR(fs, lane)];
            f16x8 al = *(const f16x8*)&R2[FR(16 + fs, lane)];
            oa = mfma16(ah, Fh, oa); oa = mfma16(ah, Fl, oa); oa = mfma16(al, Fh, oa);
            int f2 = (fs + 2) & 15;
            Fh = KH[f2*64]; Fl = KL[f2*64];
            f16x8 ah2 = *(const f16x8*)&R2[FR(fs + 1, lane)];
            f16x8 al2 = *(const f16x8*)&R2[FR(16 + fs + 1, lane)];
            oa = mfma16(ah2, Gh, oa); oa = mfma16(ah2, Gl, oa); oa = mfma16(al2, Gh, oa);
        }

        float* ob = out + ((size_t)b*NN + t0) * DVV + w*32 + i;
        #pragma unroll
        for (int r = 0; r < 16; ++r) {
            int tok = rowf(r, q);
            ob[(size_t)tok * DVV] = oa[r] * __builtin_amdgcn_rcpf(norms[tok]);
        }
    }
}

extern "C" void kernel_launch(void* const* d_in, const int* in_sizes, int n_in,
                              void* d_out, int out_size, void* d_ws, size_t ws_size,
                              hipStream_t stream) {
    const float* Q     = (const float*)d_in[0];
    const float* K     = (const float*)d_in[1];
    const float* V     = (const float*)d_in[2];
    const float* mask  = (const float*)d_in[3];
    const float* omega = (const float*)d_in[4];
    float* out = (float*)d_out;

    char* ws = (char*)d_ws;
    _Float16* omh    = (_Float16*)(ws);                       // 64 KB
    _Float16* oml    = (_Float16*)(ws + (64 << 10));          // 64 KB
    unsigned* kmaxord = (unsigned*)(ws + (128 << 10));        // 32 B
    float*    ksum   = (float*)(ws + (132 << 10));            // 8 KB
    float*    pks    = (float*)(ws + (140 << 10));            // 256 KB
    _Float16* kvph   = (_Float16*)(ws + (400 << 10));         // 512 KB
    _Float16* kvpl   = (_Float16*)(ws + (912 << 10));         // 512 KB
    float*    pkv    = (float*)(ws + (2 << 20));              // 32 MB

    pack_kernel<<<16, 256, 0, stream>>>(omega, omh, oml, kmaxord);
    kmax_kernel<<<dim3(64, BB), 256, 0, stream>>>(K, omh, kmaxord);
    kv_kernel<<<dim3(64, BB), 256, 0, stream>>>(K, V, mask, omh, oml, kmaxord, pkv, pks);
    reduce_kernel<<<dim3(128, BB), 256, 0, stream>>>(pkv, pks, ksum, kvph, kvpl);
    out_kernel<<<dim3(64, BB), 256, 0, stream>>>(Q, mask, omh, oml, ksum, kvph, kvpl, out);
}